// Round 1
// baseline (1099.511 us; speedup 1.0000x reference)
//
#include <hip/hip_runtime.h>

#define N_NODES 100000
#define N_EDGES 3200000

// ---------------- CSR build ----------------

__global__ void hist_kernel(const int* __restrict__ dst, int* __restrict__ cnt, int e) {
    int i = blockIdx.x * blockDim.x + threadIdx.x;
    if (i < e) atomicAdd(&cnt[dst[i]], 1);
}

__global__ void scan_kernel(const int* __restrict__ cnt, int* __restrict__ rp, int n) {
    __shared__ int tile[1024];
    int tx = threadIdx.x;
    int carry = 0;
    for (int base = 0; base < n; base += 1024) {
        int i = base + tx;
        int v = (i < n) ? cnt[i] : 0;
        tile[tx] = v;
        __syncthreads();
        #pragma unroll
        for (int off = 1; off < 1024; off <<= 1) {
            int t = (tx >= off) ? tile[tx - off] : 0;
            __syncthreads();
            tile[tx] += t;
            __syncthreads();
        }
        if (i < n) rp[i] = carry + tile[tx] - v;  // exclusive
        carry += tile[1023];
        __syncthreads();
    }
    if (tx == 0) rp[n] = carry;
}

__global__ void scatter_kernel(const int* __restrict__ dst, const int* __restrict__ src,
                               const float* __restrict__ w, int e,
                               const int* __restrict__ rp, int* __restrict__ fill,
                               int* __restrict__ es, float* __restrict__ ew) {
    int i = blockIdx.x * blockDim.x + threadIdx.x;
    if (i < e) {
        int d = dst[i];
        int pos = rp[d] + atomicAdd(&fill[d], 1);
        es[pos] = src[i];
        ew[pos] = w[i];
    }
}

// ---------------- CSR SpMM ----------------
// one wave per dst row; lanes parallel over features; serial over edges

__global__ void spmm_f128(const int* __restrict__ es, const float* __restrict__ ew,
                          const int* __restrict__ rp, const float* __restrict__ feat,
                          float* __restrict__ out, int n) {
    int row = blockIdx.x * 4 + (threadIdx.x >> 6);
    if (row >= n) return;
    int f = (threadIdx.x & 63) * 2;
    int beg = rp[row], end = rp[row + 1];
    float ax = 0.f, ay = 0.f;
    #pragma unroll 4
    for (int e = beg; e < end; ++e) {
        int s = es[e];
        float wv = ew[e];
        float2 v = *reinterpret_cast<const float2*>(feat + (size_t)s * 128 + f);
        ax += wv * v.x;
        ay += wv * v.y;
    }
    float2 r; r.x = ax; r.y = ay;
    *reinterpret_cast<float2*>(out + (size_t)row * 128 + f) = r;
}

__global__ void spmm_f64_bias(const int* __restrict__ es, const float* __restrict__ ew,
                              const int* __restrict__ rp, const float* __restrict__ feat,
                              const float* __restrict__ bias, float* __restrict__ out, int n) {
    int row = blockIdx.x * 4 + (threadIdx.x >> 6);
    if (row >= n) return;
    int f = threadIdx.x & 63;
    int beg = rp[row], end = rp[row + 1];
    float acc = 0.f;
    #pragma unroll 4
    for (int e = beg; e < end; ++e) {
        acc += ew[e] * feat[(size_t)es[e] * 64 + f];
    }
    out[(size_t)row * 64 + f] = acc + bias[f];
}

// ---------------- dense GEMMs (f32 vector ALU; no fp32 MFMA on CDNA4) ----------------

// s[N,128] @ W1[128,256] + b1, relu -> h[N,256].  16 rows/block, 256 threads (col=tx).
__global__ void gemm1_kernel(const float* __restrict__ A, const float* __restrict__ W,
                             const float* __restrict__ bias, float* __restrict__ out) {
    __shared__ float4 tile[16][32];  // 16 rows x 128 k
    int tx = threadIdx.x;
    int row0 = blockIdx.x * 16;
    #pragma unroll
    for (int i = 0; i < 2; ++i) {
        int idx = i * 256 + tx;
        int r = idx >> 5, c = idx & 31;
        tile[r][c] = *reinterpret_cast<const float4*>(A + (size_t)(row0 + r) * 128 + c * 4);
    }
    __syncthreads();
    int col = tx;
    float acc[16];
    #pragma unroll
    for (int r = 0; r < 16; ++r) acc[r] = 0.f;
    for (int k4 = 0; k4 < 32; ++k4) {
        float w0 = W[(k4 * 4 + 0) * 256 + col];
        float w1 = W[(k4 * 4 + 1) * 256 + col];
        float w2 = W[(k4 * 4 + 2) * 256 + col];
        float w3 = W[(k4 * 4 + 3) * 256 + col];
        #pragma unroll
        for (int r = 0; r < 16; ++r) {
            float4 a = tile[r][k4];  // broadcast within wave
            acc[r] += a.x * w0 + a.y * w1 + a.z * w2 + a.w * w3;
        }
    }
    float b = bias[col];
    #pragma unroll
    for (int r = 0; r < 16; ++r) {
        float v = acc[r] + b;
        out[(size_t)(row0 + r) * 256 + col] = fmaxf(v, 0.f);
    }
}

// h[N,256] @ W2[256,64] -> g[N,64].  32 rows/block, 256 threads (col=tx&63, 4 row-groups).
__global__ void gemm2_kernel(const float* __restrict__ A, const float* __restrict__ W,
                             float* __restrict__ out) {
    __shared__ float4 tile[32][64];  // 32 rows x 256 k  (32 KiB)
    int tx = threadIdx.x;
    int row0 = blockIdx.x * 32;
    #pragma unroll
    for (int i = 0; i < 8; ++i) {
        int idx = i * 256 + tx;
        int r = idx >> 6, c = idx & 63;
        tile[r][c] = *reinterpret_cast<const float4*>(A + (size_t)(row0 + r) * 256 + c * 4);
    }
    __syncthreads();
    int col = tx & 63;
    int rg = tx >> 6;
    float acc[8];
    #pragma unroll
    for (int r = 0; r < 8; ++r) acc[r] = 0.f;
    for (int k4 = 0; k4 < 64; ++k4) {
        float w0 = W[(k4 * 4 + 0) * 64 + col];
        float w1 = W[(k4 * 4 + 1) * 64 + col];
        float w2 = W[(k4 * 4 + 2) * 64 + col];
        float w3 = W[(k4 * 4 + 3) * 64 + col];
        #pragma unroll
        for (int r = 0; r < 8; ++r) {
            float4 a = tile[rg * 8 + r][k4];  // wave-uniform row-group -> broadcast
            acc[r] += a.x * w0 + a.y * w1 + a.z * w2 + a.w * w3;
        }
    }
    #pragma unroll
    for (int r = 0; r < 8; ++r) {
        out[(size_t)(row0 + rg * 8 + r) * 64 + col] = acc[r];
    }
}

// ---------------- launch ----------------

extern "C" void kernel_launch(void* const* d_in, const int* in_sizes, int n_in,
                              void* d_out, int out_size, void* d_ws, size_t ws_size,
                              hipStream_t stream) {
    const float* x     = (const float*)d_in[0];
    const int*   ei    = (const int*)d_in[1];
    const float* ew_in = (const float*)d_in[2];
    const float* W1    = (const float*)d_in[3];
    const float* b1    = (const float*)d_in[4];
    const float* W2    = (const float*)d_in[5];
    const float* b2    = (const float*)d_in[6];
    float* outp = (float*)d_out;

    const int n = N_NODES, e = N_EDGES;
    const int* dst = ei;       // edge_index[0]
    const int* src = ei + e;   // edge_index[1]

    char* ws = (char*)d_ws;
    size_t off = 0;
    auto alloc = [&](size_t bytes) {
        void* p = ws + off;
        off += (bytes + 255) & ~size_t(255);
        return p;
    };
    int*   es   = (int*)alloc(sizeof(int) * (size_t)e);
    float* ews  = (float*)alloc(sizeof(float) * (size_t)e);
    int*   cnt  = (int*)alloc(sizeof(int) * (size_t)n * 2);  // cnt + fill
    int*   fill = cnt + n;
    int*   rp   = (int*)alloc(sizeof(int) * (size_t)(n + 1));
    float* sbuf = (float*)alloc(sizeof(float) * (size_t)n * 128);
    float* hbuf = (float*)alloc(sizeof(float) * (size_t)n * 256);
    float* gbuf = sbuf;  // s is dead after gemm1; reuse region for g [N,64]

    hipMemsetAsync(cnt, 0, sizeof(int) * (size_t)n * 2, stream);
    hist_kernel<<<(e + 255) / 256, 256, 0, stream>>>(dst, cnt, e);
    scan_kernel<<<1, 1024, 0, stream>>>(cnt, rp, n);
    scatter_kernel<<<(e + 255) / 256, 256, 0, stream>>>(dst, src, ew_in, e, rp, fill, es, ews);

    // layer 1 (restructured): s = A @ x ; h = relu(s @ W1 + b1)
    spmm_f128<<<(n + 3) / 4, 256, 0, stream>>>(es, ews, rp, x, sbuf, n);
    gemm1_kernel<<<n / 16, 256, 0, stream>>>(sbuf, W1, b1, hbuf);

    // layer 2: g = h @ W2 ; out = A @ g + b2
    gemm2_kernel<<<n / 32, 256, 0, stream>>>(hbuf, W2, gbuf);
    spmm_f64_bias<<<(n + 3) / 4, 256, 0, stream>>>(es, ews, rp, gbuf, b2, outp, n);
}

// Round 2
// 838.571 us; speedup vs baseline: 1.3112x; 1.3112x over previous
//
#include <hip/hip_runtime.h>

#define N_NODES 100000
#define N_EDGES 3200000

// ---------------- CSR build ----------------

__global__ void hist_kernel(const int* __restrict__ dst, int* __restrict__ cnt, int e) {
    int i = blockIdx.x * blockDim.x + threadIdx.x;
    if (i < e) atomicAdd(&cnt[dst[i]], 1);
}

// pass 1: per-1024-block inclusive scan -> exclusive within block; block sums out
__global__ void scan1_kernel(const int* __restrict__ cnt, int* __restrict__ rp,
                             int* __restrict__ bsum, int n) {
    __shared__ int tile[1024];
    int tx = threadIdx.x;
    int i = blockIdx.x * 1024 + tx;
    int v = (i < n) ? cnt[i] : 0;
    tile[tx] = v;
    __syncthreads();
    #pragma unroll
    for (int off = 1; off < 1024; off <<= 1) {
        int t = (tx >= off) ? tile[tx - off] : 0;
        __syncthreads();
        tile[tx] += t;
        __syncthreads();
    }
    if (i < n) rp[i] = tile[tx] - v;  // exclusive within block
    if (tx == 1023) bsum[blockIdx.x] = tile[1023];
}

// pass 2: one block exclusive-scans the <=128 block sums; writes grand total to rp[n]
__global__ void scan2_kernel(int* __restrict__ bsum, int* __restrict__ rp, int nb, int n) {
    __shared__ int tile[128];
    int tx = threadIdx.x;
    int v = (tx < nb) ? bsum[tx] : 0;
    tile[tx] = v;
    __syncthreads();
    #pragma unroll
    for (int off = 1; off < 128; off <<= 1) {
        int t = (tx >= off) ? tile[tx - off] : 0;
        __syncthreads();
        tile[tx] += t;
        __syncthreads();
    }
    if (tx < nb) bsum[tx] = tile[tx] - v;  // exclusive
    if (tx == 127) rp[n] = tile[127];
}

// pass 3: add block offsets
__global__ void scan3_kernel(int* __restrict__ rp, const int* __restrict__ bsum, int n) {
    int i = blockIdx.x * 1024 + threadIdx.x;
    if (i < n) rp[i] += bsum[blockIdx.x];
}

// packed (src, weight) single 8B write per edge: one dirty line instead of two
__global__ void scatter_kernel(const int* __restrict__ dst, const int* __restrict__ src,
                               const float* __restrict__ w, int e,
                               const int* __restrict__ rp, int* __restrict__ fill,
                               int2* __restrict__ ep) {
    int i = blockIdx.x * blockDim.x + threadIdx.x;
    if (i < e) {
        int d = dst[i];
        int pos = rp[d] + atomicAdd(&fill[d], 1);
        int2 p;
        p.x = src[i];
        p.y = __float_as_int(w[i]);
        ep[pos] = p;
    }
}

// ---------------- CSR SpMM ----------------
// one wave per dst row; lanes parallel over features; serial over edges

__global__ void spmm_f128(const int2* __restrict__ ep, const int* __restrict__ rp,
                          const float* __restrict__ feat, float* __restrict__ out, int n) {
    int row = blockIdx.x * 4 + (threadIdx.x >> 6);
    if (row >= n) return;
    int f = (threadIdx.x & 63) * 2;
    int beg = rp[row], end = rp[row + 1];
    float ax = 0.f, ay = 0.f;
    #pragma unroll 4
    for (int e = beg; e < end; ++e) {
        int2 p = ep[e];
        float wv = __int_as_float(p.y);
        float2 v = *reinterpret_cast<const float2*>(feat + (size_t)p.x * 128 + f);
        ax += wv * v.x;
        ay += wv * v.y;
    }
    float2 r; r.x = ax; r.y = ay;
    *reinterpret_cast<float2*>(out + (size_t)row * 128 + f) = r;
}

__global__ void spmm_f64_bias(const int2* __restrict__ ep, const int* __restrict__ rp,
                              const float* __restrict__ feat, const float* __restrict__ bias,
                              float* __restrict__ out, int n) {
    int row = blockIdx.x * 4 + (threadIdx.x >> 6);
    if (row >= n) return;
    int f = threadIdx.x & 63;
    int beg = rp[row], end = rp[row + 1];
    float acc = 0.f;
    #pragma unroll 4
    for (int e = beg; e < end; ++e) {
        int2 p = ep[e];
        acc += __int_as_float(p.y) * feat[(size_t)p.x * 64 + f];
    }
    out[(size_t)row * 64 + f] = acc + bias[f];
}

// ---------------- dense GEMMs (f32 vector ALU; no fp32 MFMA on CDNA4) ----------------
// register-tiled: each thread owns 4 cols (float4) x 8 rows -> 16 FMA per ds_read_b128

// s[N,128] @ W1[128,256] + b1, relu -> h[N,256].  32 rows/block, 256 threads.
__global__ void gemm1_kernel(const float* __restrict__ A, const float* __restrict__ W,
                             const float* __restrict__ bias, float* __restrict__ out) {
    __shared__ float4 tile[32][32];  // 32 rows x 128 k  (16 KiB)
    int tx = threadIdx.x;
    int row0 = blockIdx.x * 32;
    #pragma unroll
    for (int i = 0; i < 4; ++i) {
        int idx = i * 256 + tx;
        int r = idx >> 5, c = idx & 31;
        tile[r][c] = *reinterpret_cast<const float4*>(A + (size_t)(row0 + r) * 128 + c * 4);
    }
    __syncthreads();
    int w = tx >> 6;   // wave -> rows w*8..w*8+7
    int l = tx & 63;   // cols 4l..4l+3
    float4 acc[8];
    #pragma unroll
    for (int r = 0; r < 8; ++r) { acc[r].x = acc[r].y = acc[r].z = acc[r].w = 0.f; }
    for (int k4 = 0; k4 < 32; ++k4) {
        float4 wv0 = *reinterpret_cast<const float4*>(W + (size_t)(k4 * 4 + 0) * 256 + l * 4);
        float4 wv1 = *reinterpret_cast<const float4*>(W + (size_t)(k4 * 4 + 1) * 256 + l * 4);
        float4 wv2 = *reinterpret_cast<const float4*>(W + (size_t)(k4 * 4 + 2) * 256 + l * 4);
        float4 wv3 = *reinterpret_cast<const float4*>(W + (size_t)(k4 * 4 + 3) * 256 + l * 4);
        #pragma unroll
        for (int r = 0; r < 8; ++r) {
            float4 a = tile[w * 8 + r][k4];  // wave-uniform -> LDS broadcast
            acc[r].x += a.x * wv0.x + a.y * wv1.x + a.z * wv2.x + a.w * wv3.x;
            acc[r].y += a.x * wv0.y + a.y * wv1.y + a.z * wv2.y + a.w * wv3.y;
            acc[r].z += a.x * wv0.z + a.y * wv1.z + a.z * wv2.z + a.w * wv3.z;
            acc[r].w += a.x * wv0.w + a.y * wv1.w + a.z * wv2.w + a.w * wv3.w;
        }
    }
    float4 bv = *reinterpret_cast<const float4*>(bias + l * 4);
    #pragma unroll
    for (int r = 0; r < 8; ++r) {
        float4 v;
        v.x = fmaxf(acc[r].x + bv.x, 0.f);
        v.y = fmaxf(acc[r].y + bv.y, 0.f);
        v.z = fmaxf(acc[r].z + bv.z, 0.f);
        v.w = fmaxf(acc[r].w + bv.w, 0.f);
        *reinterpret_cast<float4*>(out + (size_t)(row0 + w * 8 + r) * 256 + l * 4) = v;
    }
}

// h[N,256] @ W2[256,64] -> g[N,64].  32 rows/block, 256 threads.
// lane: col group cg=(l&15)*4, row-sub s=l>>4 (pad 65 -> s-groups hit distinct banks)
__global__ void gemm2_kernel(const float* __restrict__ A, const float* __restrict__ W,
                             float* __restrict__ out) {
    __shared__ float4 tile[32][65];  // 32 rows x 256 k, padded (33.3 KiB)
    int tx = threadIdx.x;
    int row0 = blockIdx.x * 32;
    #pragma unroll
    for (int i = 0; i < 8; ++i) {
        int idx = i * 256 + tx;
        int r = idx >> 6, c = idx & 63;
        tile[r][c] = *reinterpret_cast<const float4*>(A + (size_t)(row0 + r) * 256 + c * 4);
    }
    __syncthreads();
    int w = tx >> 6;
    int l = tx & 63;
    int cg = (l & 15) * 4;  // cols cg..cg+3
    int s = l >> 4;         // row-sub 0..3
    int rbase = w * 8 + s * 2;
    float4 acc[2];
    #pragma unroll
    for (int r = 0; r < 2; ++r) { acc[r].x = acc[r].y = acc[r].z = acc[r].w = 0.f; }
    for (int k4 = 0; k4 < 64; ++k4) {
        float4 wv0 = *reinterpret_cast<const float4*>(W + (size_t)(k4 * 4 + 0) * 64 + cg);
        float4 wv1 = *reinterpret_cast<const float4*>(W + (size_t)(k4 * 4 + 1) * 64 + cg);
        float4 wv2 = *reinterpret_cast<const float4*>(W + (size_t)(k4 * 4 + 2) * 64 + cg);
        float4 wv3 = *reinterpret_cast<const float4*>(W + (size_t)(k4 * 4 + 3) * 64 + cg);
        #pragma unroll
        for (int r = 0; r < 2; ++r) {
            float4 a = tile[rbase + r][k4];
            acc[r].x += a.x * wv0.x + a.y * wv1.x + a.z * wv2.x + a.w * wv3.x;
            acc[r].y += a.x * wv0.y + a.y * wv1.y + a.z * wv2.y + a.w * wv3.y;
            acc[r].z += a.x * wv0.z + a.y * wv1.z + a.z * wv2.z + a.w * wv3.z;
            acc[r].w += a.x * wv0.w + a.y * wv1.w + a.z * wv2.w + a.w * wv3.w;
        }
    }
    #pragma unroll
    for (int r = 0; r < 2; ++r) {
        *reinterpret_cast<float4*>(out + (size_t)(row0 + rbase + r) * 64 + cg) = acc[r];
    }
}

// ---------------- launch ----------------

extern "C" void kernel_launch(void* const* d_in, const int* in_sizes, int n_in,
                              void* d_out, int out_size, void* d_ws, size_t ws_size,
                              hipStream_t stream) {
    const float* x     = (const float*)d_in[0];
    const int*   ei    = (const int*)d_in[1];
    const float* ew_in = (const float*)d_in[2];
    const float* W1    = (const float*)d_in[3];
    const float* b1    = (const float*)d_in[4];
    const float* W2    = (const float*)d_in[5];
    const float* b2    = (const float*)d_in[6];
    float* outp = (float*)d_out;

    const int n = N_NODES, e = N_EDGES;
    const int* dst = ei;       // edge_index[0]
    const int* src = ei + e;   // edge_index[1]

    char* ws = (char*)d_ws;
    size_t off = 0;
    auto alloc = [&](size_t bytes) {
        void* p = ws + off;
        off += (bytes + 255) & ~size_t(255);
        return p;
    };
    int2*  ep   = (int2*)alloc(sizeof(int2) * (size_t)e);
    int*   cnt  = (int*)alloc(sizeof(int) * (size_t)n * 2);  // cnt + fill
    int*   fill = cnt + n;
    int*   rp   = (int*)alloc(sizeof(int) * (size_t)(n + 1));
    int*   bsum = (int*)alloc(sizeof(int) * 256);
    float* sbuf = (float*)alloc(sizeof(float) * (size_t)n * 128);
    float* hbuf = (float*)alloc(sizeof(float) * (size_t)n * 256);
    float* gbuf = sbuf;  // s dead after gemm1; reuse for g [N,64]

    const int nb = (n + 1023) / 1024;  // 98

    hipMemsetAsync(cnt, 0, sizeof(int) * (size_t)n * 2, stream);
    hist_kernel<<<(e + 255) / 256, 256, 0, stream>>>(dst, cnt, e);
    scan1_kernel<<<nb, 1024, 0, stream>>>(cnt, rp, bsum, n);
    scan2_kernel<<<1, 128, 0, stream>>>(bsum, rp, nb, n);
    scan3_kernel<<<nb, 1024, 0, stream>>>(rp, bsum, n);
    scatter_kernel<<<(e + 255) / 256, 256, 0, stream>>>(dst, src, ew_in, e, rp, fill, ep);

    // layer 1 (restructured): s = A @ x ; h = relu(s @ W1 + b1)
    spmm_f128<<<(n + 3) / 4, 256, 0, stream>>>(ep, rp, x, sbuf, n);
    gemm1_kernel<<<n / 32, 256, 0, stream>>>(sbuf, W1, b1, hbuf);

    // layer 2: g = h @ W2 ; out = A @ g + b2
    gemm2_kernel<<<n / 32, 256, 0, stream>>>(hbuf, W2, gbuf);
    spmm_f64_bias<<<(n + 3) / 4, 256, 0, stream>>>(ep, rp, gbuf, b2, outp, n);
}